// Round 2
// baseline (372.982 us; speedup 1.0000x reference)
//
#include <hip/hip_runtime.h>
#include <stdint.h>

// Problem constants
#define NB   64          // batches
#define NS   64          // sensors
#define NT   2030        // time samples
#define NP   16384       // ROI*ROI pixels
#define DAS_ELEMS (NB * NP)          // 1,048,576
#define PIX_ELEMS ((size_t)NB * NS * NP)

// native clang vector type (usable with __builtin_nontemporal_store)
typedef float v4f __attribute__((ext_vector_type(4)));

// ---------------------------------------------------------------------------
// Kernel 0: transpose geometry (pixel,s) -> (s,pixel), fusing clamp + valid.
//   tc[s*NP + p] = clamp(t_idx[p*NS + s], 0, NT-1)
//   wv[s*NP + p] = (0 <= t < NT) ? weights[p*NS + s] : 0
// 256 blocks x 256 threads; each block handles a 64-pixel x 64-s tile via LDS.
// ---------------------------------------------------------------------------
__global__ __launch_bounds__(256) void prep_kernel(
    const int* __restrict__ t_idx, const float* __restrict__ w,
    int* __restrict__ tc, float* __restrict__ wv)
{
    __shared__ int   ti[64][65];
    __shared__ float wf[64][65];
    const int pbase = blockIdx.x * 64;

    // coalesced load of the tile: flat input range [pbase*64, (pbase+64)*64)
    #pragma unroll
    for (int k = 0; k < 16; ++k) {
        int o = k * 256 + threadIdx.x;     // 0..4095
        int r = o >> 6, s = o & 63;        // r = pixel-in-tile, s = sensor
        ti[r][s] = t_idx[pbase * 64 + o];
        wf[r][s] = w[pbase * 64 + o];
    }
    __syncthreads();

    // transposed write: for fixed s, 64 consecutive pixels
    #pragma unroll
    for (int k = 0; k < 16; ++k) {
        int o = k * 256 + threadIdx.x;
        int s = o >> 6, r = o & 63;
        int t = ti[r][s];
        bool valid = (t >= 0) & (t < NT);
        int tcl = min(max(t, 0), NT - 1);
        tc[s * NP + pbase + r] = tcl;
        wv[s * NP + pbase + r] = valid ? wf[r][s] : 0.0f;
    }
}

// ---------------------------------------------------------------------------
// Kernel 1: main DAS. grid (16 pixel-tiles, 64 batches) x 256 threads.
// Each thread owns 4 consecutive pixels; loops over all 64 sensors.
// TR=true : geometry pre-transposed in ws (fast path)
// TR=false: read original layout directly (ws-too-small fallback)
// ---------------------------------------------------------------------------
template <bool TR>
__global__ __launch_bounds__(256) void main_kernel(
    const float* __restrict__ sino,   // (B, S, T)
    const int*   __restrict__ tptr,
    const float* __restrict__ wptr,
    float*       __restrict__ das,    // (B, NP) raw relu'd output
    float*       __restrict__ pix,    // (B, S, NP)
    unsigned*    __restrict__ bmax)   // per-batch max (float bits)
{
    const int b = blockIdx.y;
    const int p = blockIdx.x * 1024 + threadIdx.x * 4;
    const float* __restrict__ srow = sino + (size_t)b * (NS * NT);
    float* __restrict__ pixb = pix + (size_t)b * ((size_t)NS * NP) + p;

    v4f acc = (v4f)(0.0f);

    for (int s = 0; s < NS; ++s) {
        int4 t; float wx, wy, wz, ww;
        if (TR) {
            t = *(const int4*)(tptr + s * NP + p);
            const float4 w4 = *(const float4*)(wptr + s * NP + p);
            wx = w4.x; wy = w4.y; wz = w4.z; ww = w4.w;
        } else {
            int t0 = tptr[(p + 0) * NS + s];
            int t1 = tptr[(p + 1) * NS + s];
            int t2 = tptr[(p + 2) * NS + s];
            int t3 = tptr[(p + 3) * NS + s];
            wx = ((t0 >= 0) & (t0 < NT)) ? wptr[(p + 0) * NS + s] : 0.f;
            wy = ((t1 >= 0) & (t1 < NT)) ? wptr[(p + 1) * NS + s] : 0.f;
            wz = ((t2 >= 0) & (t2 < NT)) ? wptr[(p + 2) * NS + s] : 0.f;
            ww = ((t3 >= 0) & (t3 < NT)) ? wptr[(p + 3) * NS + s] : 0.f;
            t.x = min(max(t0, 0), NT - 1);
            t.y = min(max(t1, 0), NT - 1);
            t.z = min(max(t2, 0), NT - 1);
            t.w = min(max(t3, 0), NT - 1);
        }
        const float* __restrict__ sr = srow + s * NT;
        v4f v;
        v.x = sr[t.x] * wx;
        v.y = sr[t.y] * wy;
        v.z = sr[t.z] * wz;
        v.w = sr[t.w] * ww;
        // streaming store: never re-read, keep it out of L2
        __builtin_nontemporal_store(v, (v4f*)(pixb + (size_t)s * NP));
        acc += v;
    }

    // relu
    acc.x = fmaxf(acc.x, 0.f); acc.y = fmaxf(acc.y, 0.f);
    acc.z = fmaxf(acc.z, 0.f); acc.w = fmaxf(acc.w, 0.f);
    *(v4f*)(das + (size_t)b * NP + p) = acc;

    // block max -> per-batch atomic max
    float m = fmaxf(fmaxf(acc.x, acc.y), fmaxf(acc.z, acc.w));
    #pragma unroll
    for (int off = 32; off > 0; off >>= 1)
        m = fmaxf(m, __shfl_down(m, off, 64));
    __shared__ float wm[4];
    if ((threadIdx.x & 63) == 0) wm[threadIdx.x >> 6] = m;
    __syncthreads();
    if (threadIdx.x == 0) {
        m = fmaxf(fmaxf(wm[0], wm[1]), fmaxf(wm[2], wm[3]));
        atomicMax(&bmax[b], __float_as_uint(m));   // all values >= 0: uint order == float order
    }
}

// ---------------------------------------------------------------------------
// Kernel 2: normalize das in place. 1M elems / 4 per thread.
// ---------------------------------------------------------------------------
__global__ __launch_bounds__(256) void norm_kernel(
    float* __restrict__ das, const unsigned* __restrict__ bmax)
{
    int idx = (blockIdx.x * 256 + threadIdx.x) * 4;
    int b = idx >> 14;                   // NP = 16384 pixels per batch
    float m = __uint_as_float(bmax[b]);
    m = (m > 1e-8f) ? m : 1.0f;
    v4f v = *(v4f*)(das + idx);
    v.x = v.x / m; v.y = v.y / m; v.z = v.z / m; v.w = v.w / m;
    *(v4f*)(das + idx) = v;
}

extern "C" void kernel_launch(void* const* d_in, const int* in_sizes, int n_in,
                              void* d_out, int out_size, void* d_ws, size_t ws_size,
                              hipStream_t stream)
{
    const float* sino  = (const float*)d_in[0];   // (64,1,64,2030) f32
    const float* w     = (const float*)d_in[1];   // (128,128,64)   f32
    const int*   t_idx = (const int*)  d_in[2];   // (128,128,64)   i32
    // d_in[3] (valid_mask) intentionally unused: valid == (0 <= t_idx < NT)

    float* das = (float*)d_out;                   // first 1,048,576 floats
    float* pix = (float*)d_out + DAS_ELEMS;       // next 67,108,864 floats

    char* ws = (char*)d_ws;
    const size_t need = (size_t)(8u << 20) + 256;
    const bool big = ws_size >= need;

    unsigned* bmax;
    int* tc = nullptr; float* wv = nullptr;
    if (big) {
        tc   = (int*)ws;                          // 4 MB
        wv   = (float*)(ws + (4u << 20));         // 4 MB
        bmax = (unsigned*)(ws + (8u << 20));      // 256 B
    } else {
        bmax = (unsigned*)ws;                     // need only 256 B
    }

    (void)hipMemsetAsync(bmax, 0, NB * sizeof(unsigned), stream);

    if (big) {
        prep_kernel<<<256, 256, 0, stream>>>(t_idx, w, tc, wv);
        main_kernel<true><<<dim3(16, NB), 256, 0, stream>>>(sino, tc, wv, das, pix, bmax);
    } else {
        main_kernel<false><<<dim3(16, NB), 256, 0, stream>>>(sino, t_idx, w, das, pix, bmax);
    }
    norm_kernel<<<DAS_ELEMS / 1024, 256, 0, stream>>>(das, bmax);
}